// Round 4
// baseline (10807.543 us; speedup 1.0000x reference)
//
#include <hip/hip_runtime.h>

#define N_UNITS 2048
#define N_IN 16
#define BATCH 64
#define T_STEPS 512

// d_ws layout (bytes):
//   0        : Wsum [2048][2048] f32   (16 MiB)  = a*|Wd|*sdale[col] + (1-a)*Wn
//   16 MiB   : xT   [512][64][16] f32  (2 MiB)   inputs transposed to [t][b][i]
//   18 MiB   : reluT buf0 [512][64][4] f32 (512 KiB)  packed (k>>2)*256 + b*4 + (k&3)
//   18.5 MiB : reluT buf1             (512 KiB)
//   19 MiB   : act  [64][2048] f32    (512 KiB)  activity, [batch][unit] (= output layout)

__global__ __launch_bounds__(256) void k_wsum(const float* __restrict__ Wd,
                                              const float* __restrict__ Wn,
                                              const float* __restrict__ sdale,
                                              const float* __restrict__ alpha,
                                              float* __restrict__ Wsum) {
  int f = blockIdx.x * 256 + threadIdx.x;  // float4 index
  float a = alpha[0];
  a = fminf(fmaxf(a, 0.f), 1.f);           // Hardtanh(0,1)
  float b = 1.f - a;
  int k0 = (f * 4) & (N_UNITS - 1);        // column of first element
  float4 wd = ((const float4*)Wd)[f];
  float4 wn = ((const float4*)Wn)[f];
  float4 sd = *(const float4*)(sdale + k0);
  float4 r;
  r.x = a * fabsf(wd.x) * sd.x + b * wn.x;
  r.y = a * fabsf(wd.y) * sd.y + b * wn.y;
  r.z = a * fabsf(wd.z) * sd.z + b * wn.z;
  r.w = a * fabsf(wd.w) * sd.w + b * wn.w;
  ((float4*)Wsum)[f] = r;
}

__global__ __launch_bounds__(256) void k_xT(const float* __restrict__ in,
                                            float* __restrict__ xT) {
  int idx = blockIdx.x * 256 + threadIdx.x;   // = b*8192 + i*512 + t  (coalesced read)
  int b = idx >> 13;
  int i = (idx >> 9) & 15;
  int t = idx & 511;
  xT[t * (BATCH * N_IN) + b * N_IN + i] = in[idx];
}

__global__ __launch_bounds__(256) void k_zero(float4* __restrict__ p) {
  p[blockIdx.x * 256 + threadIdx.x] = make_float4(0.f, 0.f, 0.f, 0.f);
}

// One time step. 256 WGs x 512 thr.
// Matmul phase: wave w (SGPR via readfirstlane) owns K-slice [w*256,(w+1)*256),
//   lane = batch, per-wave acc for units u0..u0+7. Weight addresses are
//   wave-uniform -> s_load_dwordx*, SGPR operand into v_fmac_f32.
// Update phase: thread -> (b2 = tid>>3, u2 = u0 + (tid&7)) so noise/act/x/inp
//   accesses are 32B-contiguous or broadcast.
__global__ __launch_bounds__(512) void k_step(const float* __restrict__ Wsum,
                                              const float* __restrict__ rprev,
                                              float* __restrict__ rnext,
                                              float* __restrict__ act,
                                              const float* __restrict__ xT,
                                              const float* __restrict__ noise,
                                              const float* __restrict__ inp,
                                              int t) {
  const int tid = threadIdx.x;
  const int w = __builtin_amdgcn_readfirstlane(tid >> 6);  // wave id, SGPR
  const int l = tid & 63;                                  // lane = batch
  const int u0 = blockIdx.x * 8;
  const int K0 = w * 256;

  // ---- update-phase prefetches (latency hides under the k-loop) ----
  const int b2 = tid >> 3;         // batch for update phase
  const int j2 = tid & 7;          // unit offset for update phase
  const int u2 = u0 + j2;
  float nz = noise[(size_t)t * (BATCH * N_UNITS) + b2 * N_UNITS + u2];
  float aold = act[b2 * N_UNITS + u2];
  float xq[16];
  {
    const float4* xr = (const float4*)(xT + t * (BATCH * N_IN) + b2 * N_IN);
#pragma unroll
    for (int q = 0; q < 4; ++q) {
      float4 v = xr[q];
      xq[4 * q + 0] = v.x; xq[4 * q + 1] = v.y;
      xq[4 * q + 2] = v.z; xq[4 * q + 3] = v.w;
    }
  }

  // ---- matmul phase: acc[jj] = sum_{k in K-slice} relu[k][l] * Wsum[u0+jj][k]
  float acc[8] = {0.f, 0.f, 0.f, 0.f, 0.f, 0.f, 0.f, 0.f};
  const float* Wb = Wsum + (size_t)u0 * N_UNITS + K0;      // wave-uniform base
  const float4* rp = (const float4*)rprev + (K0 >> 2) * 64;  // [k/4][b] float4s

  for (int kc = 0; kc < 256; kc += 8) {
    float4 a0 = rp[kc * 16 + l];        // k = K0+kc .. +3 for batch l
    float4 a1 = rp[kc * 16 + 64 + l];   // k = K0+kc+4 .. +7
    float av[8] = {a0.x, a0.y, a0.z, a0.w, a1.x, a1.y, a1.z, a1.w};
#pragma unroll
    for (int jj = 0; jj < 8; ++jj) {
      const float* wr = Wb + jj * N_UNITS + kc;  // uniform -> s_load_dwordx8
#pragma unroll
      for (int kk = 0; kk < 8; ++kk)
        acc[jj] = fmaf(av[kk], wr[kk], acc[jj]);
    }
  }

  // ---- cross-wave K reduction: red[kslice][unit][batch], padded stride 66
  __shared__ float red[8][8][66];
#pragma unroll
  for (int jj = 0; jj < 8; ++jj) red[w][jj][l] = acc[jj];
  __syncthreads();

  // ---- update phase in (b2, u2) space ----
  float drive = 0.f;
#pragma unroll
  for (int w2 = 0; w2 < 8; ++w2) drive += red[w2][j2][b2];

  float xv = 0.f;
#pragma unroll
  for (int i = 0; i < 16; ++i)
    xv = fmaf(xq[i], fabsf(inp[i * N_UNITS + u2]), xv);
  drive += xv;

  float anew = 0.8f * aold + 0.2f * drive + nz;
  act[b2 * N_UNITS + u2] = anew;
  // relu, packed [k>>2][b][k&3] for next step's float4 loads
  rnext[((u2 >> 2) << 8) + (b2 << 2) + (u2 & 3)] = fmaxf(anew, 0.f);
}

__global__ __launch_bounds__(256) void k_trans(const float4* __restrict__ act,
                                               float4* __restrict__ out) {
  int idx = blockIdx.x * 256 + threadIdx.x;  // act already [b][u] = output layout
  out[idx] = act[idx];
}

__global__ __launch_bounds__(256) void k_out(const float* __restrict__ act,
                                             const float* __restrict__ outw,
                                             float* __restrict__ out) {
  __shared__ float red[256];
  int b = blockIdx.x, tid = threadIdx.x;
  float p = 0.f;
  for (int u = tid; u < N_UNITS; u += 256)
    p = fmaf(act[b * N_UNITS + u], outw[u], p);
  red[tid] = p;
  __syncthreads();
  for (int s = 128; s > 0; s >>= 1) {
    if (tid < s) red[tid] += red[tid + s];
    __syncthreads();
  }
  if (tid == 0) out[b] = red[0];
}

extern "C" void kernel_launch(void* const* d_in, const int* in_sizes, int n_in,
                              void* d_out, int out_size, void* d_ws, size_t ws_size,
                              hipStream_t stream) {
  const float* inputs = (const float*)d_in[0];  // [64,16,512]
  const float* noise  = (const float*)d_in[1];  // [512,64,2048]
  const float* inp    = (const float*)d_in[2];  // [16,2048]
  const float* Wn     = (const float*)d_in[3];  // [2048,2048]
  const float* Wd     = (const float*)d_in[4];  // [2048,2048]
  const float* outw   = (const float*)d_in[5];  // [2048]
  const float* alpha  = (const float*)d_in[6];  // [1]
  const float* sdale  = (const float*)d_in[7];  // [2048]
  float* out = (float*)d_out;                   // [64] ++ [64*2048]

  char* ws = (char*)d_ws;
  float* Wsum  = (float*)(ws);
  float* xT    = (float*)(ws + (16u << 20));
  float* relu0 = (float*)(ws + (18u << 20));
  float* relu1 = (float*)(ws + (18u << 20) + (512u << 10));
  float* act   = (float*)(ws + (19u << 20));

  // setup: Wsum (4M f32 / float4), x transpose, zero relu0+relu1+act (1.5 MiB)
  k_wsum<<<4096, 256, 0, stream>>>(Wd, Wn, sdale, alpha, Wsum);
  k_xT<<<2048, 256, 0, stream>>>(inputs, xT);
  k_zero<<<384, 256, 0, stream>>>((float4*)relu0);

  float* rb[2] = {relu0, relu1};
  for (int t = 0; t < T_STEPS; ++t) {
    k_step<<<256, 512, 0, stream>>>(Wsum, rb[t & 1], rb[(t & 1) ^ 1], act, xT,
                                    noise, inp, t);
  }

  k_trans<<<128, 256, 0, stream>>>((const float4*)act, (float4*)(out + BATCH));
  k_out<<<64, 256, 0, stream>>>(act, outw, out);
}

// Round 5
// 8645.808 us; speedup vs baseline: 1.2500x; 1.2500x over previous
//
#include <hip/hip_runtime.h>

#define N_UNITS 2048
#define N_IN 16
#define BATCH 64
#define T_STEPS 512

// d_ws layout (bytes):
//   0        : Wsum [2048][2048] f32   (16 MiB)  = a*|Wd|*sdale[col] + (1-a)*Wn
//   16 MiB   : xT   [512][64][16] f32  (2 MiB)   inputs transposed to [t][b][i]
//   18 MiB   : reluT buf0 [512][64][4] f32 (512 KiB)  packed (k>>2)*256 + b*4 + (k&3)
//   18.5 MiB : reluT buf1             (512 KiB)
//   19 MiB   : act  [64][2048] f32    (512 KiB)  activity, [batch][unit] (= output layout)

__global__ __launch_bounds__(256) void k_wsum(const float* __restrict__ Wd,
                                              const float* __restrict__ Wn,
                                              const float* __restrict__ sdale,
                                              const float* __restrict__ alpha,
                                              float* __restrict__ Wsum) {
  int f = blockIdx.x * 256 + threadIdx.x;  // float4 index
  float a = alpha[0];
  a = fminf(fmaxf(a, 0.f), 1.f);           // Hardtanh(0,1)
  float b = 1.f - a;
  int k0 = (f * 4) & (N_UNITS - 1);        // column of first element
  float4 wd = ((const float4*)Wd)[f];
  float4 wn = ((const float4*)Wn)[f];
  float4 sd = *(const float4*)(sdale + k0);
  float4 r;
  r.x = a * fabsf(wd.x) * sd.x + b * wn.x;
  r.y = a * fabsf(wd.y) * sd.y + b * wn.y;
  r.z = a * fabsf(wd.z) * sd.z + b * wn.z;
  r.w = a * fabsf(wd.w) * sd.w + b * wn.w;
  ((float4*)Wsum)[f] = r;
}

__global__ __launch_bounds__(256) void k_xT(const float* __restrict__ in,
                                            float* __restrict__ xT) {
  int idx = blockIdx.x * 256 + threadIdx.x;   // = b*8192 + i*512 + t  (coalesced read)
  int b = idx >> 13;
  int i = (idx >> 9) & 15;
  int t = idx & 511;
  xT[t * (BATCH * N_IN) + b * N_IN + i] = in[idx];
}

__global__ __launch_bounds__(256) void k_zero(float4* __restrict__ p) {
  p[blockIdx.x * 256 + threadIdx.x] = make_float4(0.f, 0.f, 0.f, 0.f);
}

// One time step. 512 WGs x 512 thr; WG owns 4 units (u0 = blockIdx.x*4).
// 2 WG/CU -> 4 waves/SIMD (latency hiding for scalar weight loads).
// Matmul phase: wave w (SGPR via readfirstlane) owns K-slice [w*256,(w+1)*256),
//   lane = batch. Weight addresses wave-uniform -> s_load_dwordx16 (K step 16),
//   SGPR operand into v_fmac_f32.
// Update phase: threads 0..255 -> (b2 = tid>>2, u2 = u0 + (tid&3)).
__global__ __launch_bounds__(512) void k_step(const float* __restrict__ Wsum,
                                              const float* __restrict__ rprev,
                                              float* __restrict__ rnext,
                                              float* __restrict__ act,
                                              const float* __restrict__ xT,
                                              const float* __restrict__ noise,
                                              const float* __restrict__ inp,
                                              int t) {
  const int tid = threadIdx.x;
  const int w = __builtin_amdgcn_readfirstlane(tid >> 6);  // wave id, SGPR
  const int l = tid & 63;                                  // lane = batch
  const int u0 = blockIdx.x * 4;
  const int K0 = w * 256;

  // ---- update-phase prefetches (latency hides under the k-loop) ----
  const int b2 = tid >> 2;         // batch for update phase (valid when tid<256)
  const int j2 = tid & 3;          // unit offset for update phase
  const int u2 = u0 + j2;
  float nz = 0.f, aold = 0.f;
  float xq[16];
  if (tid < 256) {
    nz = noise[(size_t)t * (BATCH * N_UNITS) + b2 * N_UNITS + u2];
    aold = act[b2 * N_UNITS + u2];
    const float4* xr = (const float4*)(xT + t * (BATCH * N_IN) + b2 * N_IN);
#pragma unroll
    for (int q = 0; q < 4; ++q) {
      float4 v = xr[q];
      xq[4 * q + 0] = v.x; xq[4 * q + 1] = v.y;
      xq[4 * q + 2] = v.z; xq[4 * q + 3] = v.w;
    }
  }

  // ---- matmul phase: acc[jj] = sum_{k in K-slice} relu[k][l] * Wsum[u0+jj][k]
  float acc[4] = {0.f, 0.f, 0.f, 0.f};
  const float* Wb = Wsum + (size_t)u0 * N_UNITS + K0;        // wave-uniform base
  const float4* rp = (const float4*)rprev + (K0 >> 2) * 64;  // [k/4][b] float4s

  for (int kc = 0; kc < 256; kc += 16) {
    float av[16];
#pragma unroll
    for (int q = 0; q < 4; ++q) {
      float4 a0 = rp[(kc >> 2) * 64 + q * 64 + l];  // k = K0+kc+4q .. +3, batch l
      av[4 * q + 0] = a0.x; av[4 * q + 1] = a0.y;
      av[4 * q + 2] = a0.z; av[4 * q + 3] = a0.w;
    }
#pragma unroll
    for (int jj = 0; jj < 4; ++jj) {
      const float* wr = Wb + jj * N_UNITS + kc;  // uniform -> s_load_dwordx16
#pragma unroll
      for (int kk = 0; kk < 16; ++kk)
        acc[jj] = fmaf(av[kk], wr[kk], acc[jj]);
    }
  }

  // ---- cross-wave K reduction: red[kslice][unit][batch], padded stride 66
  __shared__ float red[8][4][66];
#pragma unroll
  for (int jj = 0; jj < 4; ++jj) red[w][jj][l] = acc[jj];
  __syncthreads();

  // ---- update phase in (b2, u2) space, threads 0..255 ----
  if (tid < 256) {
    float drive = 0.f;
#pragma unroll
    for (int w2 = 0; w2 < 8; ++w2) drive += red[w2][j2][b2];

    float xv = 0.f;
#pragma unroll
    for (int i = 0; i < 16; ++i)
      xv = fmaf(xq[i], fabsf(inp[i * N_UNITS + u2]), xv);
    drive += xv;

    float anew = 0.8f * aold + 0.2f * drive + nz;
    act[b2 * N_UNITS + u2] = anew;
    // relu, packed [k>>2][b][k&3] for next step's float4 loads
    rnext[((u2 >> 2) << 8) + (b2 << 2) + (u2 & 3)] = fmaxf(anew, 0.f);
  }
}

__global__ __launch_bounds__(256) void k_trans(const float4* __restrict__ act,
                                               float4* __restrict__ out) {
  int idx = blockIdx.x * 256 + threadIdx.x;  // act already [b][u] = output layout
  out[idx] = act[idx];
}

__global__ __launch_bounds__(256) void k_out(const float* __restrict__ act,
                                             const float* __restrict__ outw,
                                             float* __restrict__ out) {
  __shared__ float red[256];
  int b = blockIdx.x, tid = threadIdx.x;
  float p = 0.f;
  for (int u = tid; u < N_UNITS; u += 256)
    p = fmaf(act[b * N_UNITS + u], outw[u], p);
  red[tid] = p;
  __syncthreads();
  for (int s = 128; s > 0; s >>= 1) {
    if (tid < s) red[tid] += red[tid + s];
    __syncthreads();
  }
  if (tid == 0) out[b] = red[0];
}

extern "C" void kernel_launch(void* const* d_in, const int* in_sizes, int n_in,
                              void* d_out, int out_size, void* d_ws, size_t ws_size,
                              hipStream_t stream) {
  const float* inputs = (const float*)d_in[0];  // [64,16,512]
  const float* noise  = (const float*)d_in[1];  // [512,64,2048]
  const float* inp    = (const float*)d_in[2];  // [16,2048]
  const float* Wn     = (const float*)d_in[3];  // [2048,2048]
  const float* Wd     = (const float*)d_in[4];  // [2048,2048]
  const float* outw   = (const float*)d_in[5];  // [2048]
  const float* alpha  = (const float*)d_in[6];  // [1]
  const float* sdale  = (const float*)d_in[7];  // [2048]
  float* out = (float*)d_out;                   // [64] ++ [64*2048]

  char* ws = (char*)d_ws;
  float* Wsum  = (float*)(ws);
  float* xT    = (float*)(ws + (16u << 20));
  float* relu0 = (float*)(ws + (18u << 20));
  float* relu1 = (float*)(ws + (18u << 20) + (512u << 10));
  float* act   = (float*)(ws + (19u << 20));

  // setup: Wsum (4M f32 / float4), x transpose, zero relu0+relu1+act (1.5 MiB)
  k_wsum<<<4096, 256, 0, stream>>>(Wd, Wn, sdale, alpha, Wsum);
  k_xT<<<2048, 256, 0, stream>>>(inputs, xT);
  k_zero<<<384, 256, 0, stream>>>((float4*)relu0);

  float* rb[2] = {relu0, relu1};
  for (int t = 0; t < T_STEPS; ++t) {
    k_step<<<512, 512, 0, stream>>>(Wsum, rb[t & 1], rb[(t & 1) ^ 1], act, xT,
                                    noise, inp, t);
  }

  k_trans<<<128, 256, 0, stream>>>((const float4*)act, (float4*)(out + BATCH));
  k_out<<<64, 256, 0, stream>>>(act, outw, out);
}

// Round 6
// 6765.862 us; speedup vs baseline: 1.5974x; 1.2779x over previous
//
#include <hip/hip_runtime.h>

#define N_UNITS 2048
#define N_IN 16
#define BATCH 64
#define T_STEPS 512

typedef __attribute__((ext_vector_type(8))) short bf16x8;
typedef __attribute__((ext_vector_type(4))) float f32x4;
typedef __attribute__((ext_vector_type(4))) unsigned short u16x4;

// d_ws layout (bytes):
//  0        : Ap  [128 mtile][130 chunk][64 lane][8] bf16  (17,039,360 B)
//             chunks 0..63 = W_hi, 64..127 = W_lo, 128..129 = |inp| hi/hi/lo/0 block
//  17039360 : Bx  [512 t][4 nt][2 c2][64 lane][8] bf16     (4 MiB) x-term B-frags
//  21233664 : Br0 [4 nt][128 chunk][64 lane][8] bf16       (512 KiB) r̂ frags (hi|lo)
//  21757952 : Br1                                           (512 KiB)
//  22282240 : act [64 b][2048 u] f32                        (512 KiB, = output layout)
#define AP_OFF   0
#define BX_OFF   17039360
#define BR0_OFF  21233664
#define BR1_OFF  21757952
#define ACT_OFF  22282240

__device__ __forceinline__ unsigned short f2bf(float f) {
  unsigned int u = __float_as_uint(f);
  u += 0x7FFFu + ((u >> 16) & 1u);   // RNE
  return (unsigned short)(u >> 16);
}
__device__ __forceinline__ float bf2f(unsigned short h) {
  return __uint_as_float(((unsigned int)h) << 16);
}

// Pack A = [W_hi | W_lo | x-block] into MFMA fragment order.
// wave wid = mtile*130 + c; lane l: A[m][k], m = mtile*16+(l&15), k = c*32+(l>>4)*8+j.
__global__ __launch_bounds__(256) void k_packA(const float* __restrict__ Wd,
                                               const float* __restrict__ Wn,
                                               const float* __restrict__ sdale,
                                               const float* __restrict__ alphap,
                                               const float* __restrict__ inp,
                                               unsigned short* __restrict__ Ap) {
  int wid = blockIdx.x * 4 + (threadIdx.x >> 6);
  int l = threadIdx.x & 63;
  int mtile = wid / 130;
  int c = wid - mtile * 130;
  float a = fminf(fmaxf(alphap[0], 0.f), 1.f);  // Hardtanh(0,1)
  float bb = 1.f - a;
  int u = mtile * 16 + (l & 15);
  int kb = (l >> 4) * 8;
  unsigned short o[8];
  if (c < 128) {
    int k0 = (c & 63) * 32 + kb;
    bool lo = (c >= 64);
    const float* wd = Wd + (size_t)u * 2048 + k0;
    const float* wn = Wn + (size_t)u * 2048 + k0;
    const float* sd = sdale + k0;
#pragma unroll
    for (int j = 0; j < 8; ++j) {
      float v = a * fabsf(wd[j]) * sd[j] + bb * wn[j];  // Wsum[u][k]
      unsigned short h = f2bf(v);
      o[j] = lo ? f2bf(v - bf2f(h)) : h;
    }
  } else {
    int cw = c - 128;
#pragma unroll
    for (int j = 0; j < 8; ++j) {
      int kk = cw * 32 + kb + j;       // 0..63
      int sect = kk >> 4, i = kk & 15; // sect: 0 inp_hi,1 inp_hi,2 inp_lo,3 zero
      float v = fabsf(inp[i * 2048 + u]);
      unsigned short h = f2bf(v);
      o[j] = (sect == 3) ? (unsigned short)0
                         : (sect == 2 ? f2bf(v - bf2f(h)) : h);
    }
  }
  unsigned short* dst = Ap + ((size_t)wid * 64 + l) * 8;
  *(u16x4*)dst = u16x4{o[0], o[1], o[2], o[3]};
  *(u16x4*)(dst + 4) = u16x4{o[4], o[5], o[6], o[7]};
}

// Pack x-term B-frags for all t. wave wid = t*8 + nt*2 + c2.
// B[k][n]: n = nt*16+(l&15)=batch, kk = c2*32+(l>>4)*8+j; sect: 0 x_hi,1 x_lo,2 x_hi,3 0.
__global__ __launch_bounds__(256) void k_packBx(const float* __restrict__ inputs,
                                                unsigned short* __restrict__ Bx) {
  int wid = blockIdx.x * 4 + (threadIdx.x >> 6);
  int l = threadIdx.x & 63;
  int t = wid >> 3, r = wid & 7, nt = r >> 1, c2 = r & 1;
  int b = nt * 16 + (l & 15);
  int kb = (l >> 4) * 8;
  unsigned short o[8];
#pragma unroll
  for (int j = 0; j < 8; ++j) {
    int kk = c2 * 32 + kb + j;
    int sect = kk >> 4, i = kk & 15;
    float x = inputs[(size_t)b * 8192 + i * 512 + t];  // inputs[b][i][t]
    unsigned short h = f2bf(x);
    o[j] = (sect == 3) ? (unsigned short)0
                       : (sect == 1 ? f2bf(x - bf2f(h)) : h);
  }
  unsigned short* dst = Bx + ((size_t)wid * 64 + l) * 8;
  *(u16x4*)dst = u16x4{o[0], o[1], o[2], o[3]};
  *(u16x4*)(dst + 4) = u16x4{o[4], o[5], o[6], o[7]};
}

__global__ __launch_bounds__(256) void k_zero(float4* __restrict__ p) {
  p[blockIdx.x * 256 + threadIdx.x] = make_float4(0.f, 0.f, 0.f, 0.f);
}

#define MFMA(A, B, C) __builtin_amdgcn_mfma_f32_16x16x32_bf16(A, B, C, 0, 0, 0)

// One step. 128 WGs x 4 waves. WG: 16 units x 64 batch. Wave w: K-quarter
// (chunks w*16..w*16+15); per chunk: A_hi,A_lo + 8 B-frags -> 12 MFMAs over
// 4 independent acc chains (nt). x-block on waves 0,1. LDS reduce, fused update.
__global__ __launch_bounds__(256, 1) void k_step(
    const unsigned short* __restrict__ Ap,
    const unsigned short* __restrict__ Brc,
    unsigned short* __restrict__ Brn,
    const unsigned short* __restrict__ Bxt,
    const float* __restrict__ noise_t,
    float* __restrict__ act) {
  const int tid = threadIdx.x;
  const int w = __builtin_amdgcn_readfirstlane(tid >> 6);
  const int l = tid & 63;
  const int u0 = blockIdx.x * 16;

  const unsigned short* Aw = Ap + ((size_t)blockIdx.x * 130) * 512 + l * 8;
  const unsigned short* Bl = Brc + l * 8;

  f32x4 acc0 = {0.f, 0.f, 0.f, 0.f}, acc1 = acc0, acc2 = acc0, acc3 = acc0;

  const int cbase = w * 16;
#pragma unroll 2
  for (int cc = 0; cc < 16; ++cc) {
    const int c = cbase + cc;
    bf16x8 ah = *(const bf16x8*)(Aw + (size_t)c * 512);
    bf16x8 al = *(const bf16x8*)(Aw + (size_t)(64 + c) * 512);
    bf16x8 bh0 = *(const bf16x8*)(Bl + (size_t)(0 * 128 + c) * 512);
    bf16x8 bh1 = *(const bf16x8*)(Bl + (size_t)(1 * 128 + c) * 512);
    bf16x8 bh2 = *(const bf16x8*)(Bl + (size_t)(2 * 128 + c) * 512);
    bf16x8 bh3 = *(const bf16x8*)(Bl + (size_t)(3 * 128 + c) * 512);
    bf16x8 bl0 = *(const bf16x8*)(Bl + (size_t)(0 * 128 + 64 + c) * 512);
    bf16x8 bl1 = *(const bf16x8*)(Bl + (size_t)(1 * 128 + 64 + c) * 512);
    bf16x8 bl2 = *(const bf16x8*)(Bl + (size_t)(2 * 128 + 64 + c) * 512);
    bf16x8 bl3 = *(const bf16x8*)(Bl + (size_t)(3 * 128 + 64 + c) * 512);
    acc0 = MFMA(ah, bh0, acc0);  // W_hi · r_hi
    acc1 = MFMA(ah, bh1, acc1);
    acc2 = MFMA(ah, bh2, acc2);
    acc3 = MFMA(ah, bh3, acc3);
    acc0 = MFMA(ah, bl0, acc0);  // W_hi · r_lo
    acc1 = MFMA(ah, bl1, acc1);
    acc2 = MFMA(ah, bl2, acc2);
    acc3 = MFMA(ah, bl3, acc3);
    acc0 = MFMA(al, bh0, acc0);  // W_lo · r_hi
    acc1 = MFMA(al, bh1, acc1);
    acc2 = MFMA(al, bh2, acc2);
    acc3 = MFMA(al, bh3, acc3);
  }
  if (w < 2) {  // x-term chunks (2 of them) on waves 0,1
    bf16x8 ax = *(const bf16x8*)(Aw + (size_t)(128 + w) * 512);
    bf16x8 bx0 = *(const bf16x8*)(Bxt + (size_t)(0 * 2 + w) * 512 + l * 8);
    bf16x8 bx1 = *(const bf16x8*)(Bxt + (size_t)(1 * 2 + w) * 512 + l * 8);
    bf16x8 bx2 = *(const bf16x8*)(Bxt + (size_t)(2 * 2 + w) * 512 + l * 8);
    bf16x8 bx3 = *(const bf16x8*)(Bxt + (size_t)(3 * 2 + w) * 512 + l * 8);
    acc0 = MFMA(ax, bx0, acc0);
    acc1 = MFMA(ax, bx1, acc1);
    acc2 = MFMA(ax, bx2, acc2);
    acc3 = MFMA(ax, bx3, acc3);
  }

  // update-phase global loads (issued before barrier; latency hides under reduce)
  const int b = tid >> 2;
  const int ub = (tid & 3) * 4;
  const int ug = u0 + ub;
  const float4 nz = *(const float4*)(noise_t + (size_t)b * 2048 + ug);
  const float4 ao = *(const float4*)(act + (size_t)b * 2048 + ug);

  // cross-wave reduce: D[m][n]: m=(l>>4)*4+q, n=nt*16+(l&15)
  __shared__ float red[4][16][66];
  const int rl = l & 15, rh = l >> 4;
#pragma unroll
  for (int q = 0; q < 4; ++q) {
    red[w][rh * 4 + q][0 + rl] = acc0[q];
    red[w][rh * 4 + q][16 + rl] = acc1[q];
    red[w][rh * 4 + q][32 + rl] = acc2[q];
    red[w][rh * 4 + q][48 + rl] = acc3[q];
  }
  __syncthreads();

  float dr[4];
#pragma unroll
  for (int i = 0; i < 4; ++i)
    dr[i] = red[0][ub + i][b] + red[1][ub + i][b] +
            red[2][ub + i][b] + red[3][ub + i][b];

  float4 an;
  an.x = 0.8f * ao.x + 0.2f * dr[0] + nz.x;
  an.y = 0.8f * ao.y + 0.2f * dr[1] + nz.y;
  an.z = 0.8f * ao.z + 0.2f * dr[2] + nz.z;
  an.w = 0.8f * ao.w + 0.2f * dr[3] + nz.w;
  *(float4*)(act + (size_t)b * 2048 + ug) = an;

  // write r̂ = relu(an) hi/lo directly in B-frag layout for next step
  float rr[4] = {fmaxf(an.x, 0.f), fmaxf(an.y, 0.f),
                 fmaxf(an.z, 0.f), fmaxf(an.w, 0.f)};
  u16x4 hv, lv;
#pragma unroll
  for (int i = 0; i < 4; ++i) {
    unsigned short h = f2bf(rr[i]);
    hv[i] = h;
    lv[i] = f2bf(rr[i] - bf2f(h));
  }
  const int c = ug >> 5;                         // k-chunk (k = source unit)
  const int kk = ug & 31;
  const int lane_b = (b & 15) + 16 * (kk >> 3);
  const int j = kk & 7;                          // {0,4}, u16x4-aligned
  const int nt = b >> 4;
  unsigned short* dst = Brn + ((size_t)(nt * 128 + c) * 64 + lane_b) * 8 + j;
  *(u16x4*)dst = hv;
  *(u16x4*)(dst + 32768) = lv;                   // chunk c+64 (r_lo region)
}

__global__ __launch_bounds__(256) void k_trans(const float4* __restrict__ act,
                                               float4* __restrict__ out) {
  int idx = blockIdx.x * 256 + threadIdx.x;  // act already [b][u] = output layout
  out[idx] = act[idx];
}

__global__ __launch_bounds__(256) void k_out(const float* __restrict__ act,
                                             const float* __restrict__ outw,
                                             float* __restrict__ out) {
  __shared__ float red[256];
  int b = blockIdx.x, tid = threadIdx.x;
  float p = 0.f;
  for (int u = tid; u < N_UNITS; u += 256)
    p = fmaf(act[b * N_UNITS + u], outw[u], p);
  red[tid] = p;
  __syncthreads();
  for (int s = 128; s > 0; s >>= 1) {
    if (tid < s) red[tid] += red[tid + s];
    __syncthreads();
  }
  if (tid == 0) out[b] = red[0];
}

extern "C" void kernel_launch(void* const* d_in, const int* in_sizes, int n_in,
                              void* d_out, int out_size, void* d_ws, size_t ws_size,
                              hipStream_t stream) {
  const float* inputs = (const float*)d_in[0];  // [64,16,512]
  const float* noise  = (const float*)d_in[1];  // [512,64,2048]
  const float* inp    = (const float*)d_in[2];  // [16,2048]
  const float* Wn     = (const float*)d_in[3];  // [2048,2048]
  const float* Wd     = (const float*)d_in[4];  // [2048,2048]
  const float* outw   = (const float*)d_in[5];  // [2048]
  const float* alpha  = (const float*)d_in[6];  // [1]
  const float* sdale  = (const float*)d_in[7];  // [2048]
  float* out = (float*)d_out;                   // [64] ++ [64*2048]

  char* ws = (char*)d_ws;
  unsigned short* Ap  = (unsigned short*)(ws + AP_OFF);
  unsigned short* Bx  = (unsigned short*)(ws + BX_OFF);
  unsigned short* Br0 = (unsigned short*)(ws + BR0_OFF);
  unsigned short* Br1 = (unsigned short*)(ws + BR1_OFF);
  float* act          = (float*)(ws + ACT_OFF);

  k_packA<<<4160, 256, 0, stream>>>(Wd, Wn, sdale, alpha, inp, Ap);
  k_packBx<<<1024, 256, 0, stream>>>(inputs, Bx);
  k_zero<<<384, 256, 0, stream>>>((float4*)(ws + BR0_OFF));  // Br0|Br1|act = 1.5 MiB

  unsigned short* rb[2] = {Br0, Br1};
  for (int t = 0; t < T_STEPS; ++t) {
    k_step<<<128, 256, 0, stream>>>(Ap, rb[t & 1], rb[(t & 1) ^ 1],
                                    Bx + (size_t)t * 4096,
                                    noise + (size_t)t * 131072, act);
  }

  k_trans<<<128, 256, 0, stream>>>((const float4*)act, (float4*)(out + BATCH));
  k_out<<<64, 256, 0, stream>>>(act, outw, out);
}